// Round 23
// baseline (123.664 us; speedup 1.0000x reference)
//
#include <hip/hip_runtime.h>
#include <hip/hip_bf16.h>

#define B_   32
#define L_   2048
#define CIN  256
#define HID  512
#define TL   32
#define TPT  8                     // tiles per block = 256 rows
#define NGRP 256                   // 256-row groups
#define NBLK (NGRP * 2)            // x2 col-halves = 512 blocks = 2/CU

// 2*log2(e): baked into Wc/bc so the gemm output feeds exp2 directly.
#define TANH_SCALE 2.885390081777927

typedef __bf16 bf16_t;
typedef __bf16 bf16x8 __attribute__((ext_vector_type(8)));
typedef __bf16 bf16x4 __attribute__((ext_vector_type(4)));
typedef float  f32x4  __attribute__((ext_vector_type(4)));

// LDS map (64 KB): A dbuf only: buf*32768 + pipe*16384 + row*512 (swizzled)
#define APIPE 16384u
#define ABUF  32768u

// ---------------------------------------------------------------------------
// Kernel 1: compose Wc = TANH_SCALE * (W2 @ W1) (fp32 -> bf16),
//           bc = TANH_SCALE * (W2 @ b1 + b2).   (R21-proven shape)
// ---------------------------------------------------------------------------
__global__ void compose_kernel(const float* __restrict__ W1, const float* __restrict__ W2,
                               const float* __restrict__ b1, const float* __restrict__ b2,
                               bf16_t* __restrict__ Wc, float* __restrict__ bc)
{
    const int g = blockIdx.x;            // 512
    const int c = threadIdx.x;           // 256
    const float* w2row = W2 + (size_t)g * HID;
    float s[8] = {0.f, 0.f, 0.f, 0.f, 0.f, 0.f, 0.f, 0.f};
    for (int h = 0; h < HID; h += 8) {
#pragma unroll
        for (int k = 0; k < 8; ++k)
            s[k] = fmaf(w2row[h + k], W1[(size_t)(h + k) * CIN + c], s[k]);
    }
    float tot = ((s[0] + s[1]) + (s[2] + s[3])) + ((s[4] + s[5]) + (s[6] + s[7]));
    Wc[(size_t)g * CIN + c] = (bf16_t)(tot * (float)TANH_SCALE);
    if (c == 0) {
        float t0 = 0.f, t1 = 0.f;
        for (int h = 0; h < HID; h += 2) {
            t0 = fmaf(w2row[h], b1[h], t0);
            t1 = fmaf(w2row[h + 1], b1[h + 1], t1);
        }
        bc[g] = (t0 + t1 + b2[g]) * (float)TANH_SCALE;
    }
}

// ---------------------------------------------------------------------------
// Kernel 2: fused GEMM + tanh-pair-product + row-reduction.
// Block = (256-row grp, 256-col half): stage dup x2 (was x4 in R21). Wave
// owns 32 cols x BOTH pipes x 2 row-frags (TL=32): per kk 4 ds_reads : 8
// MFMA (ratio 2) with NO TY exchange (pair product in-register) and 1
// barrier per 32 rows (half of R21's per-row barrier rate). LDS = A dbuf
// only (64 KB) -> 2 blocks/CU = 16 waves. W reloads from L1/L2 per tile by
// compiler choice — R22 proved pinning it costs more occupancy than it
// saves. Stage split early/late (ve/vl) keeps peak regs ~105 <= 128 @
// (512,4). XCD pairing: both halves of a grp on one XCD's L2.
// Tripwires: WRITE_SIZE <1MB (spill), Occupancy ~48 (2 blocks resident).
// ---------------------------------------------------------------------------
__global__ __launch_bounds__(512, 4)
void fused_kernel(const float* __restrict__ x, const float* __restrict__ y,
                  const bf16_t* __restrict__ Wc, const float* __restrict__ bc,
                  float* __restrict__ partial)
{
    __shared__ char U[65536];

    const int tid  = threadIdx.x;
    const int lane = tid & 63;
    const int wv   = tid >> 6;           // wave 0..7
    const int l15  = lane & 15;
    const int l4   = lane >> 4;

    // XCD pairing: d = (grp&7) + 8*half + 16*(grp>>3)  (bijective)
    const int d    = blockIdx.x;
    const int grp  = (d & 7) + 8 * (d >> 4);
    const int half = (d >> 3) & 1;
    const int gc0  = half * 256 + wv * 32;   // this wave's output-col base

    // bias fragments (scaled)
    f32x4 bcv[2];
#pragma unroll
    for (int cj = 0; cj < 2; ++cj) {
        float4 t4 = *reinterpret_cast<const float4*>(bc + gc0 + cj * 16 + l4 * 4);
        bcv[cj] = (f32x4){t4.x, t4.y, t4.z, t4.w};
    }

    // staging identity: threads 0-255 stage x, 256-511 stage y; 8 thr/row
    const int sp   = tid >> 8;
    const int t8   = tid & 255;
    const int srow = t8 >> 3;            // row 0..31
    const int sq   = t8 & 7;             // base float4 slot
    const unsigned sswz = (unsigned)((srow & 15) << 4);
    const unsigned soff = (unsigned)(sp * APIPE + srow * 512);
    const float* sptr = (sp ? y : x) + ((size_t)grp * (TPT * TL) + srow) * CIN;

    float4 ve[4], vl[4];
    auto sloadE = [&](const float* rowbase) {
        const float4* s4 = reinterpret_cast<const float4*>(rowbase);
#pragma unroll
        for (int c = 0; c < 4; ++c) ve[c] = s4[sq + 8 * c];
    };
    auto sloadL = [&](const float* rowbase) {
        const float4* s4 = reinterpret_cast<const float4*>(rowbase);
#pragma unroll
        for (int c = 0; c < 4; ++c) vl[c] = s4[sq + 8 * (c + 4)];
    };
    auto swriteE = [&](int buf) {
        char* p = U + (unsigned)(buf * ABUF) + soff;
#pragma unroll
        for (int c = 0; c < 4; ++c) {
            const int f = sq + 8 * c;
            bf16x4 h;
            h[0] = (bf16_t)ve[c].x; h[1] = (bf16_t)ve[c].y;
            h[2] = (bf16_t)ve[c].z; h[3] = (bf16_t)ve[c].w;
            *reinterpret_cast<bf16x4*>(p + (((unsigned)(8 * f)) ^ sswz)) = h;
        }
    };
    auto swriteL = [&](int buf) {
        char* p = U + (unsigned)(buf * ABUF) + soff;
#pragma unroll
        for (int c = 0; c < 4; ++c) {
            const int f = sq + 8 * (c + 4);
            bf16x4 h;
            h[0] = (bf16_t)vl[c].x; h[1] = (bf16_t)vl[c].y;
            h[2] = (bf16_t)vl[c].z; h[3] = (bf16_t)vl[c].w;
            *reinterpret_cast<bf16x4*>(p + (((unsigned)(8 * f)) ^ sswz)) = h;
        }
    };

    // A fragment bases [pipe][ri]; per-kk addr = base ^ (kk<<6) (proven)
    unsigned ab[2][2];
#pragma unroll
    for (int pp = 0; pp < 2; ++pp)
#pragma unroll
        for (int ri = 0; ri < 2; ++ri)
            ab[pp][ri] = (unsigned)(pp * APIPE) + (unsigned)((ri * 16 + l15) * 512) +
                         (((unsigned)(l4 * 16)) ^ ((unsigned)(l15 << 4)));

    f32x4 psum[2];
    psum[0] = (f32x4){0.f, 0.f, 0.f, 0.f};
    psum[1] = (f32x4){0.f, 0.f, 0.f, 0.f};

    // prologue: stage tile 0 into buf 0
    sloadE(sptr); sloadL(sptr);
    swriteE(0);   swriteL(0);
    __syncthreads();

    for (int t = 0; t < TPT; ++t) {
        const bool pf = (t + 1 < TPT);
        const int cur = t & 1;
        const float* nptr = sptr + TL * CIN;
        if (pf) sloadE(nptr);            // early loads fly under the gemm

        // ---- gemm: both pipes, 2 row-frags, 32 cols: 4 reads : 8 MFMA / kk
        f32x4 accx[2][2], accy[2][2];    // [ri][cj]
#pragma unroll
        for (int ri = 0; ri < 2; ++ri)
#pragma unroll
            for (int cj = 0; cj < 2; ++cj) { accx[ri][cj] = bcv[cj]; accy[ri][cj] = bcv[cj]; }

        const unsigned cb = (unsigned)(cur * ABUF);
        __builtin_amdgcn_s_setprio(1);
#pragma unroll
        for (int kk = 0; kk < 8; ++kk) {
            bf16x8 w[2];
#pragma unroll
            for (int cj = 0; cj < 2; ++cj)
                w[cj] = *reinterpret_cast<const bf16x8*>(
                    Wc + (size_t)(gc0 + cj * 16 + l15) * CIN + kk * 32 + l4 * 8);
            const unsigned kx = (unsigned)(kk << 6);
            bf16x8 ax0 = *reinterpret_cast<const bf16x8*>(U + cb + (ab[0][0] ^ kx));
            bf16x8 ax1 = *reinterpret_cast<const bf16x8*>(U + cb + (ab[0][1] ^ kx));
            bf16x8 ay0 = *reinterpret_cast<const bf16x8*>(U + cb + (ab[1][0] ^ kx));
            bf16x8 ay1 = *reinterpret_cast<const bf16x8*>(U + cb + (ab[1][1] ^ kx));
#pragma unroll
            for (int cj = 0; cj < 2; ++cj) {
                accx[0][cj] = __builtin_amdgcn_mfma_f32_16x16x32_bf16(w[cj], ax0, accx[0][cj], 0, 0, 0);
                accx[1][cj] = __builtin_amdgcn_mfma_f32_16x16x32_bf16(w[cj], ax1, accx[1][cj], 0, 0, 0);
                accy[0][cj] = __builtin_amdgcn_mfma_f32_16x16x32_bf16(w[cj], ay0, accy[0][cj], 0, 0, 0);
                accy[1][cj] = __builtin_amdgcn_mfma_f32_16x16x32_bf16(w[cj], ay1, accy[1][cj], 0, 0, 0);
            }
        }
        __builtin_amdgcn_s_setprio(0);

        if (pf) {
            swriteE(cur ^ 1);            // early half into the idle buffer
            sloadL(nptr);                // late loads fly under the tanh
        }

        // ---- in-register pair product (no clamps: exp2 saturates ->
        // tanh -> +-1; per-elem rcp keeps inf safe). t = 1 - 2/(E+1).
#pragma unroll
        for (int ri = 0; ri < 2; ++ri)
#pragma unroll
            for (int cj = 0; cj < 2; ++cj)
#pragma unroll
                for (int r2 = 0; r2 < 4; ++r2) {
                    float tx = fmaf(-2.0f, __builtin_amdgcn_rcpf(exp2f(accx[ri][cj][r2]) + 1.0f), 1.0f);
                    float ty = fmaf(-2.0f, __builtin_amdgcn_rcpf(exp2f(accy[ri][cj][r2]) + 1.0f), 1.0f);
                    psum[cj][r2] = fmaf(tx, ty, psum[cj][r2]);
                }

        if (pf) swriteL(cur ^ 1);        // late half into the idle buffer
        __syncthreads();                 // publish A[cur^1]
        sptr = nptr;
    }

    // reduce over the 16 row-lanes (l15 bits; l4 indexes the col quad)
#pragma unroll
    for (int cj = 0; cj < 2; ++cj)
#pragma unroll
        for (int r2 = 0; r2 < 4; ++r2) {
            float s = psum[cj][r2];
            s += __shfl_xor(s, 1);
            s += __shfl_xor(s, 2);
            s += __shfl_xor(s, 4);
            s += __shfl_xor(s, 8);
            psum[cj][r2] = s;
        }
    if (l15 == 0) {
#pragma unroll
        for (int cj = 0; cj < 2; ++cj) {
            float4 o4 = make_float4(psum[cj][0], psum[cj][1], psum[cj][2], psum[cj][3]);
            *reinterpret_cast<float4*>(partial + (size_t)grp * HID + gc0 + cj * 16 + l4 * 4) = o4;
        }
    }
}

// ---------------------------------------------------------------------------
// Kernel 3: sum the 8 row-group partials per batch -> out[B][HID]
// (batch = 2048 rows = 8 groups of 256)
// ---------------------------------------------------------------------------
__global__ void reduce_kernel(const float* __restrict__ partial, float* __restrict__ out)
{
    int b = blockIdx.x;                  // 32
    int g = threadIdx.x;                 // 512
    float s = 0.f;
#pragma unroll
    for (int k = 0; k < 8; ++k)
        s += partial[((size_t)(b * 8 + k)) * HID + g];
    out[b * HID + g] = s;
}

extern "C" void kernel_launch(void* const* d_in, const int* in_sizes, int n_in,
                              void* d_out, int out_size, void* d_ws, size_t ws_size,
                              hipStream_t stream)
{
    const float* x  = (const float*)d_in[0];
    const float* y  = (const float*)d_in[1];
    const float* W1 = (const float*)d_in[2];
    const float* b1 = (const float*)d_in[3];
    const float* W2 = (const float*)d_in[4];
    const float* b2 = (const float*)d_in[5];
    float* out = (float*)d_out;

    char* ws = (char*)d_ws;
    bf16_t* Wc     = (bf16_t*)ws;                    // 256 KB
    float*  bc     = (float*)(ws + (256 << 10));     // 2 KB
    float*  partial = (float*)(ws + (264 << 10));    // 512 KB (256 grps x 512)

    hipLaunchKernelGGL(compose_kernel, dim3(HID), dim3(CIN), 0, stream, W1, W2, b1, b2, Wc, bc);
    hipLaunchKernelGGL(fused_kernel, dim3(NBLK), dim3(512), 0, stream, x, y, Wc, bc, partial);
    hipLaunchKernelGGL(reduce_kernel, dim3(B_), dim3(512), 0, stream, partial, out);
}

// Round 24
// 87.418 us; speedup vs baseline: 1.4146x; 1.4146x over previous
//
#include <hip/hip_runtime.h>
#include <hip/hip_bf16.h>

#define B_   32
#define L_   2048
#define CIN  256
#define HID  512
#define TL   16
#define TPT  16                    // tiles per block = 256 rows
#define NGRP 256                   // 256-row groups
#define NBLK (NGRP * 4)            // x4 col-quarters = 1024 blocks = 4/CU

// 2*log2(e): baked into Wc/bc so the gemm output feeds exp2 directly.
#define TANH_SCALE 2.885390081777927

typedef __bf16 bf16_t;
typedef __bf16 bf16x8 __attribute__((ext_vector_type(8)));
typedef __bf16 bf16x4 __attribute__((ext_vector_type(4)));
typedef float  f32x4  __attribute__((ext_vector_type(4)));

// LDS map (48 KB):
//   A dbuf @0:      buf*16384 + pipe*8192 + row*512 (swizzled rows)
//   TY dbuf @32768: buf*8192 + wq*1536 + cj*768 + l15*48 + l4*8  (<=2-way)
#define APIPE  8192u
#define ABUF   16384u
#define TY_OFF 32768u

// ---------------------------------------------------------------------------
// Kernel 0: zero d_out (re-run every call: fused kernel accumulates into it)
// ---------------------------------------------------------------------------
__global__ void zero_out_kernel(float* __restrict__ out)
{
    out[blockIdx.x * 256 + threadIdx.x] = 0.f;   // 64 blocks x 256 = 16384
}

// ---------------------------------------------------------------------------
// Kernel 1: compose Wc = TANH_SCALE * (W2 @ W1) (fp32 -> bf16),
//           bc = TANH_SCALE * (W2 @ b1 + b2).   (R21-proven shape; bc part
//           parallelized over wave 0 instead of one serial thread)
// ---------------------------------------------------------------------------
__global__ void compose_kernel(const float* __restrict__ W1, const float* __restrict__ W2,
                               const float* __restrict__ b1, const float* __restrict__ b2,
                               bf16_t* __restrict__ Wc, float* __restrict__ bc)
{
    const int g = blockIdx.x;            // 512
    const int c = threadIdx.x;           // 256
    const float* w2row = W2 + (size_t)g * HID;
    float s[8] = {0.f, 0.f, 0.f, 0.f, 0.f, 0.f, 0.f, 0.f};
    for (int h = 0; h < HID; h += 8) {
#pragma unroll
        for (int k = 0; k < 8; ++k)
            s[k] = fmaf(w2row[h + k], W1[(size_t)(h + k) * CIN + c], s[k]);
    }
    float tot = ((s[0] + s[1]) + (s[2] + s[3])) + ((s[4] + s[5]) + (s[6] + s[7]));
    Wc[(size_t)g * CIN + c] = (bf16_t)(tot * (float)TANH_SCALE);
    if (c < 64) {                        // wave 0: parallel bc reduction
        float t = 0.f;
        for (int h = c; h < HID; h += 64)
            t = fmaf(w2row[h], b1[h], t);
#pragma unroll
        for (int off = 32; off >= 1; off >>= 1)
            t += __shfl_xor(t, off);
        if (c == 0) bc[g] = (t + b2[g]) * (float)TANH_SCALE;
    }
}

// ---------------------------------------------------------------------------
// Kernel 2: fused GEMM + tanh-pair-product + row-reduction (R21 structure,
// byte-identical gemm) with the partial buffer REPLACED by atomicAdd into
// d_out (8 adds per output element, order-independent within tolerance) —
// kills the reduce kernel + partial round-trip.
// Pipe-split ratio-2 gemm, XCD pairing, A dbuf + T14 prefetch, TY dbuf,
// 1024 blocks x 512 thr; W reloads from L1/L2 by compiler choice (R22
// proved pinning costs more occupancy than it saves).
// ---------------------------------------------------------------------------
__global__ __launch_bounds__(512, 4)
void fused_kernel(const float* __restrict__ x, const float* __restrict__ y,
                  const bf16_t* __restrict__ Wc, const float* __restrict__ bc,
                  float* __restrict__ out)
{
    __shared__ char U[49152];

    const int tid  = threadIdx.x;
    const int lane = tid & 63;
    const int wv   = tid >> 6;           // wave 0..7
    const int l15  = lane & 15;
    const int l4   = lane >> 4;

    // XCD-pairing decode: d%8 == grp%8 for all 4 q's of a grp (bijective)
    const int d    = blockIdx.x;
    const int grp  = (d & 7) + 8 * (d >> 5);
    const int q    = (d >> 3) & 3;

    const int pipe = wv >> 2;            // 0 = x-waves, 1 = y-waves
    const int wq   = wv & 3;
    const int gc0  = q * 128 + wq * 32;  // this wave's output-col base

    // --- weight fragments (compiler keeps or reloads from L1/L2 per tile)
    bf16x8 wreg[8][2];
#pragma unroll
    for (int kk = 0; kk < 8; ++kk)
#pragma unroll
        for (int cj = 0; cj < 2; ++cj)
            wreg[kk][cj] = *reinterpret_cast<const bf16x8*>(
                Wc + (size_t)(gc0 + cj * 16 + l15) * CIN + kk * 32 + l4 * 8);

    // bias fragments (scaled)
    f32x4 bcv[2];
#pragma unroll
    for (int cj = 0; cj < 2; ++cj) {
        float4 t4 = *reinterpret_cast<const float4*>(bc + gc0 + cj * 16 + l4 * 4);
        bcv[cj] = (f32x4){t4.x, t4.y, t4.z, t4.w};
    }

    // staging identity: threads 0-255 stage x, 256-511 stage y; 16 thr/row
    const int sp = tid >> 8;
    const int t8 = tid & 255;
    const int sr = t8 >> 4;              // row 0..15
    const int sq = t8 & 15;              // float4 slot
    const unsigned sswz = (unsigned)((sr & 15) << 4);
    const unsigned soff = (unsigned)(sp * APIPE + sr * 512);
    const float* sptr = (sp ? y : x) + ((size_t)grp * (TPT * TL) + sr) * CIN;

    float4 v[4];
    auto sload = [&](const float* rowbase) {
        const float4* s4 = reinterpret_cast<const float4*>(rowbase);
#pragma unroll
        for (int c = 0; c < 4; ++c) v[c] = s4[sq + 16 * c];
    };
    auto swrite = [&](int buf) {
        char* p = U + (unsigned)(buf * ABUF) + soff;
#pragma unroll
        for (int c = 0; c < 4; ++c) {
            const int f = sq + 16 * c;
            bf16x4 h;
            h[0] = (bf16_t)v[c].x; h[1] = (bf16_t)v[c].y;
            h[2] = (bf16_t)v[c].z; h[3] = (bf16_t)v[c].w;
            *reinterpret_cast<bf16x4*>(p + (((unsigned)(8 * f)) ^ sswz)) = h;
        }
    };

    // A fragment address (own pipe); per-kk addr = base ^ (kk<<6)
    const unsigned abase = (pipe ? APIPE : 0u) +
        (unsigned)(l15 * 512) + (((unsigned)(l4 * 16)) ^ ((unsigned)(l15 << 4)));
    // TY slot (dbuf handled by +buf*8192)
    const unsigned tyb = TY_OFF + (unsigned)(wq * 1536 + l15 * 48 + l4 * 8);

    f32x4 psum[2];
    psum[0] = (f32x4){0.f, 0.f, 0.f, 0.f};
    psum[1] = (f32x4){0.f, 0.f, 0.f, 0.f};

    // prologue: stage tile 0 into buf 0
    sload(sptr);
    swrite(0);
    __syncthreads();

    for (int t = 0; t < TPT; ++t) {
        const bool pf = (t + 1 < TPT);
        const int cur = t & 1;
        if (pf) {                        // issue tile t+1 loads early (T14)
            sptr += TL * CIN;
            sload(sptr);
        }

        // ---- gemm own pipe: 1 A-read : 2 MFMA
        f32x4 acc0 = bcv[0], acc1 = bcv[1];
        const unsigned ab = abase + (unsigned)(cur * ABUF);
        __builtin_amdgcn_s_setprio(1);
#pragma unroll
        for (int kk = 0; kk < 8; ++kk) {
            bf16x8 a = *reinterpret_cast<const bf16x8*>(U + (ab ^ (unsigned)(kk << 6)));
            acc0 = __builtin_amdgcn_mfma_f32_16x16x32_bf16(wreg[kk][0], a, acc0, 0, 0, 0);
            acc1 = __builtin_amdgcn_mfma_f32_16x16x32_bf16(wreg[kk][1], a, acc1, 0, 0, 0);
        }
        __builtin_amdgcn_s_setprio(0);

        // ---- tanh own pipe (scale baked in): t = 1 - 2/(exp2(a)+1);
        // no clamps: exp2 saturates to inf/0 -> tanh saturates to +-1.
#pragma unroll
        for (int r2 = 0; r2 < 4; ++r2) {
            acc0[r2] = fmaf(-2.0f, __builtin_amdgcn_rcpf(exp2f(acc0[r2]) + 1.0f), 1.0f);
            acc1[r2] = fmaf(-2.0f, __builtin_amdgcn_rcpf(exp2f(acc1[r2]) + 1.0f), 1.0f);
        }

        if (pipe) {                      // y-waves: publish tanh as bf16
            bf16x4 t0, t1;
#pragma unroll
            for (int r2 = 0; r2 < 4; ++r2) { t0[r2] = (bf16_t)acc0[r2]; t1[r2] = (bf16_t)acc1[r2]; }
            *reinterpret_cast<bf16x4*>(U + tyb + (unsigned)(cur * 8192))        = t0;
            *reinterpret_cast<bf16x4*>(U + tyb + (unsigned)(cur * 8192) + 768u) = t1;
        }

        if (pf) swrite(cur ^ 1);         // A(t+1) into the idle buffer

        __syncthreads();                 // publish TY[cur] + A[cur^1]

        if (!pipe) {                     // x-waves: product into psum
            bf16x4 o0 = *reinterpret_cast<const bf16x4*>(U + tyb + (unsigned)(cur * 8192));
            bf16x4 o1 = *reinterpret_cast<const bf16x4*>(U + tyb + (unsigned)(cur * 8192) + 768u);
#pragma unroll
            for (int r2 = 0; r2 < 4; ++r2) {
                psum[0][r2] = fmaf(acc0[r2], (float)o0[r2], psum[0][r2]);
                psum[1][r2] = fmaf(acc1[r2], (float)o1[r2], psum[1][r2]);
            }
        }
    }

    // x-waves: reduce over the 16 row-lanes, then atomicAdd into out
    if (!pipe) {
#pragma unroll
        for (int cj = 0; cj < 2; ++cj)
#pragma unroll
            for (int r2 = 0; r2 < 4; ++r2) {
                float s = psum[cj][r2];
                s += __shfl_xor(s, 1);
                s += __shfl_xor(s, 2);
                s += __shfl_xor(s, 4);
                s += __shfl_xor(s, 8);
                psum[cj][r2] = s;
            }
        if (l15 == 0) {
            const int b = grp >> 3;      // batch = grp/8
            float* ob = out + (size_t)b * HID + gc0 + l4 * 4;
#pragma unroll
            for (int cj = 0; cj < 2; ++cj)
#pragma unroll
                for (int r2 = 0; r2 < 4; ++r2)
                    atomicAdd(ob + cj * 16 + r2, psum[cj][r2]);
        }
    }
}

extern "C" void kernel_launch(void* const* d_in, const int* in_sizes, int n_in,
                              void* d_out, int out_size, void* d_ws, size_t ws_size,
                              hipStream_t stream)
{
    const float* x  = (const float*)d_in[0];
    const float* y  = (const float*)d_in[1];
    const float* W1 = (const float*)d_in[2];
    const float* b1 = (const float*)d_in[3];
    const float* W2 = (const float*)d_in[4];
    const float* b2 = (const float*)d_in[5];
    float* out = (float*)d_out;

    char* ws = (char*)d_ws;
    bf16_t* Wc = (bf16_t*)ws;                    // 256 KB
    float*  bc = (float*)(ws + (256 << 10));     // 2 KB

    hipLaunchKernelGGL(zero_out_kernel, dim3(B_ * HID / 256), dim3(256), 0, stream, out);
    hipLaunchKernelGGL(compose_kernel, dim3(HID), dim3(CIN), 0, stream, W1, W2, b1, b2, Wc, bc);
    hipLaunchKernelGGL(fused_kernel, dim3(NBLK), dim3(512), 0, stream, x, y, Wc, bc, out);
}